// Round 1
// baseline (1324.651 us; speedup 1.0000x reference)
//
#include <hip/hip_runtime.h>
#include <cstdint>
#include <cstddef>

#define TSTEPS 1024
#define NB 256
#define NI 128
#define NH 128
#define NC 18

typedef _Float16 half2_t __attribute__((ext_vector_type(2)));

__device__ __forceinline__ half2_t as_h2(uint32_t v){
  union { uint32_t u; half2_t h; } cv; cv.u = v; return cv.h;
}
__device__ __forceinline__ uint32_t pack_h2(float a, float b){
  half2_t h; h.x = (_Float16)a; h.y = (_Float16)b;
  union { half2_t h; uint32_t u; } cv; cv.h = h; return cv.u;
}
__device__ __forceinline__ float dot2f(half2_t a, half2_t b, float c){
#if __has_builtin(__builtin_amdgcn_fdot2)
  return __builtin_amdgcn_fdot2(a, b, c, false);   // v_dot2_f32_f16
#else
  return c + (float)a.x*(float)b.x + (float)a.y*(float)b.y;
#endif
}
__device__ __forceinline__ float fast_rcp(float x){
#if __has_builtin(__builtin_amdgcn_rcpf)
  return __builtin_amdgcn_rcpf(x);
#else
  return 1.f / x;
#endif
}
__device__ __forceinline__ float sigm(float v){
  v = fminf(fmaxf(v, -30.f), 30.f);
  return fast_rcp(1.f + __expf(-v));
}
__device__ __forceinline__ float tanhx(float v){
  v = fminf(fmaxf(v, -15.f), 15.f);
  float e = __expf(2.f*v);
  return (e - 1.f) * fast_rcp(e + 1.f);
}

// One persistent block per batch row. 512 threads: thread (c=tid&127, s=tid>>7)
// computes all 4 gates of cell c over k-slice [32s,32s+32). Weights live in
// VGPRs (128 half2) for all 1024 steps. Wave roles in phase B:
//   waves 0,1 (s=0): gate reduce + activations + c/h update
//   wave 2   (tid 128..199): fused head partials for step t-1
//   wave 4   (tid 256..319): x_{t+1} f16 staging + 2-deep HBM prefetch
//   wave 7   (tid 456..473): head finalize (in phase A, for step t-2)
__global__ __launch_bounds__(512, 2) void lstm_fused(
    const float* __restrict__ x,      // [T,B,I]
    const float* __restrict__ h0,     // [B,H]
    const float* __restrict__ c0,     // [B,H]
    const float* __restrict__ Wih,    // [4H,I]
    const float* __restrict__ Whh,    // [4H,H]
    const float* __restrict__ bih,    // [4H]
    const float* __restrict__ bhh,    // [4H]
    const float* __restrict__ fcW,    // [18,H]
    const float* __restrict__ fcb,    // [18]
    float* __restrict__ out,          // [T,B,18]
    float* __restrict__ hT,           // [B,H]
    float* __restrict__ cT)           // [B,H]
{
  const int b   = blockIdx.x;
  const int tid = threadIdx.x;
  const int c   = tid & 127;
  const int s   = tid >> 7;

  __shared__ __align__(16) uint32_t h2buf[2][64];   // h as f16 pairs, double-buffered
  __shared__ __align__(16) uint32_t x2buf[2][64];   // x_t as f16 pairs, double-buffered
  __shared__ __align__(16) float    pbuf[3][128][4]; // gate partials from s=1..3
  __shared__ __align__(16) float    hpbuf[72];       // head partials 18x4

  // ---- recurrent + input weights into registers (f16 pairs) ----
  half2_t wih[4][16], whh[4][16];
#pragma unroll
  for (int q = 0; q < 4; ++q){
    const float2* wi = (const float2*)(Wih + ((size_t)(q*128 + c))*NI + 32*s);
    const float2* wh = (const float2*)(Whh + ((size_t)(q*128 + c))*NH + 32*s);
#pragma unroll
    for (int kk = 0; kk < 16; ++kk){
      float2 fi = wi[kk];
      float2 fh = wh[kk];
      half2_t a; a.x = (_Float16)fi.x; a.y = (_Float16)fi.y; wih[q][kk] = a;
      half2_t d; d.x = (_Float16)fh.x; d.y = (_Float16)fh.y; whh[q][kk] = d;
    }
  }

  // ---- head weights (meaningful for tid 128..199) ----
  const bool is_head = (tid >= 128) && (tid < 128 + 4*NC);
  half2_t wfc[16];
  {
    int j  = is_head ? ((tid - 128) >> 2) : 0;
    int ss = tid & 3;
    const float2* wf = (const float2*)(fcW + (size_t)j*NH + 32*ss);
#pragma unroll
    for (int kk = 0; kk < 16; ++kk){
      float2 f = wf[kk];
      half2_t a; a.x = (_Float16)f.x; a.y = (_Float16)f.y; wfc[kk] = a;
    }
  }

  // biases (used by s==0 threads)
  float bq[4];
#pragma unroll
  for (int q = 0; q < 4; ++q) bq[q] = bih[q*128 + c] + bhh[q*128 + c];

  const bool is_fin = (tid >= 456) && (tid < 456 + NC);
  const float myfcb = is_fin ? fcb[tid - 456] : 0.f;

  float cst = c0[(size_t)b*NH + c];   // cell state (s==0 threads authoritative)

  // ---- prime LDS h/x buffers and the x prefetch pipeline ----
  float2 xA = make_float2(0.f, 0.f), xB = make_float2(0.f, 0.f);
  if (tid >= 256 && tid < 320){
    int cc = tid - 256;
    float2 hp0 = ((const float2*)(h0 + (size_t)b*NH))[cc];
    h2buf[0][cc] = pack_h2(hp0.x, hp0.y);
    float2 x0p = ((const float2*)(x + (size_t)b*NI))[cc];
    x2buf[0][cc] = pack_h2(x0p.x, x0p.y);
    xA = ((const float2*)(x + (size_t)1*NB*NI + (size_t)b*NI))[cc];
    xB = ((const float2*)(x + (size_t)2*NB*NI + (size_t)b*NI))[cc];
  }
  __syncthreads();

  float a0 = 0.f, a1 = 0.f, a2 = 0.f, a3 = 0.f;  // s==0 carries its partials

  for (int t = 0; t < TSTEPS; ++t){
    const int hp = t & 1;
    // ---------------- phase A: partial gate dots ----------------
    {
      const uint4* hv = (const uint4*)&h2buf[hp][16*s];   // wave-uniform -> broadcast
      const uint4* xv = (const uint4*)&x2buf[hp][16*s];
      float a[4] = {0.f, 0.f, 0.f, 0.f};
#pragma unroll
      for (int ch = 0; ch < 4; ++ch){
        uint4 hc = hv[ch];
        uint4 xc = xv[ch];
        uint32_t hw[4] = {hc.x, hc.y, hc.z, hc.w};
        uint32_t xw[4] = {xc.x, xc.y, xc.z, xc.w};
#pragma unroll
        for (int jj = 0; jj < 4; ++jj){
          half2_t hx = as_h2(hw[jj]);
          half2_t xx = as_h2(xw[jj]);
          const int kk = ch*4 + jj;
#pragma unroll
          for (int q = 0; q < 4; ++q){
            a[q] = dot2f(whh[q][kk], hx, a[q]);
            a[q] = dot2f(wih[q][kk], xx, a[q]);
          }
        }
      }
      if (s != 0){
        *(float4*)&pbuf[s-1][c][0] = make_float4(a[0], a[1], a[2], a[3]);
      } else {
        a0 = a[0]; a1 = a[1]; a2 = a[2]; a3 = a[3];
      }
      if (is_fin && t >= 2){             // finalize head for step t-2
        int j = tid - 456;
        float4 p = *(const float4*)&hpbuf[4*j];
        out[(size_t)(t-2)*NB*NC + (size_t)b*NC + j] = p.x + p.y + p.z + p.w + myfcb;
      }
    }
    __syncthreads();
    // ---------------- phase B ----------------
    if (s == 0){
      float4 p0 = *(const float4*)&pbuf[0][c][0];
      float4 p1 = *(const float4*)&pbuf[1][c][0];
      float4 p2 = *(const float4*)&pbuf[2][c][0];
      float gi = a0 + p0.x + p1.x + p2.x + bq[0];
      float gf = a1 + p0.y + p1.y + p2.y + bq[1];
      float gg = a2 + p0.z + p1.z + p2.z + bq[2];
      float go = a3 + p0.w + p1.w + p2.w + bq[3];
      float iv = sigm(gi);
      float fv = sigm(gf);
      float gv = tanhx(gg);
      float ov = sigm(go);
      cst = fv*cst + iv*gv;
      float hval = ov * tanhx(cst);
      ((_Float16*)&h2buf[hp^1][0])[c] = (_Float16)hval;  // h_t for step t+1
      if (t == TSTEPS-1){
        hT[(size_t)b*NH + c] = hval;
        cT[(size_t)b*NH + c] = cst;
      }
    } else if (is_head){
      if (t >= 1){                       // head partials for step t-1 (h in h2buf[hp])
        int ss = tid & 3;
        int j  = (tid - 128) >> 2;
        const uint4* hv2 = (const uint4*)&h2buf[hp][16*ss];
        float p = 0.f;
#pragma unroll
        for (int ch = 0; ch < 4; ++ch){
          uint4 hc = hv2[ch];
          uint32_t hw[4] = {hc.x, hc.y, hc.z, hc.w};
#pragma unroll
          for (int jj = 0; jj < 4; ++jj)
            p = dot2f(wfc[ch*4 + jj], as_h2(hw[jj]), p);
        }
        hpbuf[4*j + ss] = p;
      }
    } else if (tid >= 256 && tid < 320){
      int cc = tid - 256;
      x2buf[hp^1][cc] = pack_h2(xA.x, xA.y);   // x_{t+1} for step t+1
      xA = xB;
      int tn = (t + 3 < TSTEPS) ? (t + 3) : (TSTEPS - 1);
      xB = ((const float2*)(x + (size_t)tn*NB*NI + (size_t)b*NI))[cc];
    }
    __syncthreads();
  }

  // ---------------- epilogue: heads for t = T-2, T-1 ----------------
  if (is_fin){
    int j = tid - 456;
    float4 p = *(const float4*)&hpbuf[4*j];
    out[(size_t)(TSTEPS-2)*NB*NC + (size_t)b*NC + j] = p.x + p.y + p.z + p.w + myfcb;
  }
  __syncthreads();
  if (is_head){
    int ss = tid & 3;
    int j  = (tid - 128) >> 2;
    const uint4* hv2 = (const uint4*)&h2buf[TSTEPS & 1][16*ss];  // h_{T-1}
    float p = 0.f;
#pragma unroll
    for (int ch = 0; ch < 4; ++ch){
      uint4 hc = hv2[ch];
      uint32_t hw[4] = {hc.x, hc.y, hc.z, hc.w};
#pragma unroll
      for (int jj = 0; jj < 4; ++jj)
        p = dot2f(wfc[ch*4 + jj], as_h2(hw[jj]), p);
    }
    hpbuf[4*j + ss] = p;
  }
  __syncthreads();
  if (is_fin){
    int j = tid - 456;
    float4 p = *(const float4*)&hpbuf[4*j];
    out[(size_t)(TSTEPS-1)*NB*NC + (size_t)b*NC + j] = p.x + p.y + p.z + p.w + myfcb;
  }
}

extern "C" void kernel_launch(void* const* d_in, const int* in_sizes, int n_in,
                              void* d_out, int out_size, void* d_ws, size_t ws_size,
                              hipStream_t stream) {
  (void)in_sizes; (void)n_in; (void)d_ws; (void)ws_size; (void)out_size;
  const float* x   = (const float*)d_in[0];
  const float* h0  = (const float*)d_in[1];
  const float* c0  = (const float*)d_in[2];
  const float* Wih = (const float*)d_in[3];
  const float* Whh = (const float*)d_in[4];
  const float* bih = (const float*)d_in[5];
  const float* bhh = (const float*)d_in[6];
  const float* fcW = (const float*)d_in[7];
  const float* fcb = (const float*)d_in[8];
  float* out = (float*)d_out;
  float* hT  = out + (size_t)TSTEPS*NB*NC;   // 4,718,592
  float* cT  = hT + (size_t)NB*NH;           // +32,768
  hipLaunchKernelGGL(lstm_fused, dim3(NB), dim3(512), 0, stream,
                     x, h0, c0, Wih, Whh, bih, bhh, fcW, fcb, out, hT, cT);
}